// Round 14
// baseline (535.062 us; speedup 1.0000x reference)
//
#include <hip/hip_runtime.h>
#include <hip/hip_bf16.h>

#define HC 128
#define NHEAD 4
#define NEG 0.2f
#define NSUB 8  // XCD sub-buckets (blockIdx & 7 heuristic; correctness-independent)

typedef unsigned int uint32;
typedef __attribute__((ext_vector_type(8))) short short8v;
typedef __attribute__((ext_vector_type(4))) float f32x4;

__device__ __forceinline__ float leaky(float v) { return v > 0.f ? v : NEG * v; }
__device__ __forceinline__ int clampi(int v, int lo, int hi) { return v < lo ? lo : (v > hi ? hi : v); }

__device__ __forceinline__ uint32 pack_bf16(float lo, float hi) {
  uint32 a = __float_as_uint(lo);
  uint32 b = __float_as_uint(hi);
  a = (a + 0x7FFFu + ((a >> 16) & 1u)) >> 16;
  b = (b + 0x7FFFu + ((b >> 16) & 1u)) & 0xFFFF0000u;
  return a | b;
}
__device__ __forceinline__ unsigned short bf16_1(float v) {
  uint32 a = __float_as_uint(v);
  return (unsigned short)((a + 0x7FFFu + ((a >> 16) & 1u)) >> 16);
}
__device__ __forceinline__ float2 unpack_bf16(uint32 u) {
  return make_float2(__uint_as_float(u << 16), __uint_as_float(u & 0xFFFF0000u));
}
__device__ __forceinline__ short8v as_s8(uint4 u) {
  union { uint4 a; short8v b; } c; c.a = u; return c.b;
}

#define WT_STRIDE 18432  // 144*128

// ---------------- utility ----------------
__global__ __launch_bounds__(256) void zero_kernel(int* __restrict__ p, int n) {
  int i = blockIdx.x * 256 + threadIdx.x;
  int stride = gridDim.x * 256;
  for (; i < n; i += stride) p[i] = 0;
}

// ---------------- bucketed CSR build ----------------
// K1: count edges per (dst>>8, blockIdx&7)
__global__ __launch_bounds__(256) void bincnt_kernel(const int* __restrict__ dst, int* __restrict__ bcnt, int E, int n) {
  int e = blockIdx.x * 256 + threadIdx.x;
  if (e < E) {
    int d = clampi(dst[e], 0, n - 1);
    atomicAdd(&bcnt[(d >> 8) * NSUB + (blockIdx.x & (NSUB - 1))], 1);
  }
}

// K2: exclusive scan of NC bucket counters -> bbase, bcur (one block)
__global__ __launch_bounds__(256) void bscan_kernel(const int* __restrict__ bcnt, int* __restrict__ bbase,
                                                    int* __restrict__ bcur, int NC) {
  __shared__ int part[256];
  int t = threadIdx.x;
  int chunk = (NC + 255) >> 8;
  int lo = t * chunk; if (lo > NC) lo = NC;
  int hi = lo + chunk; if (hi > NC) hi = NC;
  int s = 0;
  for (int i = lo; i < hi; ++i) s += bcnt[i];
  part[t] = s;
  __syncthreads();
  for (int off = 1; off < 256; off <<= 1) {
    int v = (t >= off) ? part[t - off] : 0;
    __syncthreads();
    part[t] += v;
    __syncthreads();
  }
  int run = part[t] - s;
  for (int i = lo; i < hi; ++i) {
    bbase[i] = run;
    bcur[i] = run;
    run += bcnt[i];
  }
}

// K3: scatter (src,dst) pairs into sub-bucket regions
__global__ __launch_bounds__(256) void binscatter_kernel(const int* __restrict__ src, const int* __restrict__ dst,
                                                         int* __restrict__ bcur, int2* __restrict__ ebuf, int E, int n) {
  int e = blockIdx.x * 256 + threadIdx.x;
  if (e < E) {
    int d = clampi(dst[e], 0, n - 1);
    int s = clampi(src[e], 0, n - 1);
    int idx = (d >> 8) * NSUB + (blockIdx.x & (NSUB - 1));
    int p = atomicAdd(&bcur[idx], 1);
    if (p >= 0 && p < E) ebuf[p] = make_int2(s, d);
  }
}

// K4: per-bucket (256 dsts): LDS histogram + scan -> row_start, place csr
__global__ __launch_bounds__(256) void bucket_finalize(const int2* __restrict__ ebuf, const int* __restrict__ bbase,
                                                       int* __restrict__ row_start, int* __restrict__ csr,
                                                       int NBKT, int E, int n) {
  __shared__ int cnt[256];
  __shared__ int part[256];
  __shared__ int cur[256];
  int b = blockIdx.x;
  int t = threadIdx.x;
  int start = bbase[b * NSUB];
  int end = (b == NBKT - 1) ? E : bbase[(b + 1) * NSUB];
  int d0 = b << 8;
  int ndst = n - d0; if (ndst > 256) ndst = 256;
  cnt[t] = 0;
  __syncthreads();
  for (int i = start + t; i < end; i += 256) {
    int d = ebuf[i].y - d0;
    if (d >= 0 && d < 256) atomicAdd(&cnt[d], 1);
  }
  __syncthreads();
  int c = cnt[t];
  part[t] = c;
  __syncthreads();
  for (int off = 1; off < 256; off <<= 1) {
    int v = (t >= off) ? part[t - off] : 0;
    __syncthreads();
    part[t] += v;
    __syncthreads();
  }
  int excl = part[t] - c;
  if (t < ndst) row_start[d0 + t] = start + excl;
  if (b == NBKT - 1 && t == 0) row_start[n] = E;
  cur[t] = start + excl;
  __syncthreads();
  for (int i = start + t; i < end; i += 256) {
    int2 pr = ebuf[i];
    int d = pr.y - d0;
    if (d >= 0 && d < 256) {
      int p = atomicAdd(&cur[d], 1);
      if (p >= 0 && p < E) csr[p] = pr.x;
    }
  }
}

// ---------------- fused prep: xprep + W transpose + fused-alpha cols + zero-init --
// id ranges: [0,n64) x-pack; [+3*16384) Wt; [+3*2048) alpha cols;
// [+NC) zero bcnt; [+G*128) zero pooled.
__global__ __launch_bounds__(256) void prep_kernel(const float* __restrict__ x, const float* __restrict__ W0,
                                                   const float* __restrict__ W1, const float* __restrict__ W2,
                                                   const float* __restrict__ as0, const float* __restrict__ as1,
                                                   const float* __restrict__ as2, const float* __restrict__ ad0,
                                                   const float* __restrict__ ad1, const float* __restrict__ ad2,
                                                   uint32* __restrict__ X16, unsigned short* __restrict__ wt,
                                                   int* __restrict__ bcnt, float* __restrict__ pooled,
                                                   long long n64, int NC, int Gp) {
  long long id = (long long)blockIdx.x * 256 + threadIdx.x;
  if (id < n64) {
    float2 v = *(const float2*)&x[id * 2];
    X16[id] = pack_bf16(v.x, v.y);
    return;
  }
  long long id2l = id - n64;
  if (id2l < 3 * 16384) {
    int id2 = (int)id2l;
    int l = id2 >> 14;
    int r = id2 & 16383;
    int k = r >> 7, nc = r & 127;
    const float* W = l == 0 ? W0 : (l == 1 ? W1 : W2);
    wt[(size_t)l * WT_STRIDE + nc * 128 + k] = bf16_1(W[r]);
    return;
  }
  id2l -= 3 * 16384;
  if (id2l < 3 * 2048) {
    int id2 = (int)id2l;
    int l = id2 >> 11;
    int r = id2 & 2047;
    int col8 = r >> 7, k = r & 127;
    const float* W = l == 0 ? W0 : (l == 1 ? W1 : W2);
    unsigned short outv = 0;
    if (col8 < 8) {
      int h = col8 & 3;
      const float* av = (col8 < 4) ? (l == 0 ? as0 : (l == 1 ? as1 : as2))
                                   : (l == 0 ? ad0 : (l == 1 ? ad1 : ad2));
      float s = 0.f;
      for (int c = 0; c < 32; ++c) s += W[k * 128 + 32 * h + c] * av[32 * h + c];
      outv = bf16_1(s);
    }
    wt[(size_t)l * WT_STRIDE + (128 + col8) * 128 + k] = outv;
    return;
  }
  id2l -= 3 * 2048;
  if (id2l < NC) {
    bcnt[id2l] = 0;
    return;
  }
  id2l -= NC;
  if (id2l < (long long)Gp * 128) pooled[id2l] = 0.f;
}

// ---------------- MFMA GEMM: H = X @ W, As/Ad via fused 9th B-tile --------------
__global__ __launch_bounds__(256) void gemm_mfma(const uint32* __restrict__ X16, const unsigned short* __restrict__ Wt,
                                                 uint32* __restrict__ H16, float* __restrict__ As,
                                                 float* __restrict__ Ad, int n) {
  int t = threadIdx.x;
  int wave = t >> 6, lane = t & 63;
  int l15 = lane & 15, lg = lane >> 4;
  int row0 = blockIdx.x * 64 + wave * 16;
  int arow = row0 + l15;
  if (arow >= n) arow = n - 1;
  const uint4* xr = (const uint4*)(X16 + (size_t)arow * 64);
  uint4 a[4];
#pragma unroll
  for (int kc = 0; kc < 4; ++kc) a[kc] = xr[kc * 4 + lg];
  f32x4 acc[9];
#pragma unroll
  for (int nb = 0; nb < 9; ++nb) acc[nb] = (f32x4){0.f, 0.f, 0.f, 0.f};
#pragma unroll
  for (int kc = 0; kc < 4; ++kc) {
    uint4 b[9];
#pragma unroll
    for (int nb = 0; nb < 9; ++nb) {
      int ncol = nb * 16 + l15;
      b[nb] = *(const uint4*)(Wt + (size_t)ncol * 128 + kc * 32 + lg * 8);
    }
#pragma unroll
    for (int nb = 0; nb < 9; ++nb)
      acc[nb] = __builtin_amdgcn_mfma_f32_16x16x32_bf16(as_s8(a[kc]), as_s8(b[nb]), acc[nb], 0, 0, 0);
  }
#pragma unroll
  for (int r = 0; r < 4; ++r) {
    int gr = row0 + lg * 4 + r;
    bool ok = gr < n;
#pragma unroll
    for (int nb = 0; nb < 8; ++nb) {
      float mine = acc[nb][r];
      float other = __shfl_xor(mine, 1);
      if (ok && (lane & 1) == 0) H16[(size_t)gr * 64 + nb * 8 + (l15 >> 1)] = pack_bf16(mine, other);
    }
    float av = acc[8][r];
    if (ok && l15 < 4) As[gr * 4 + l15] = av;
    if (ok && l15 >= 4 && l15 < 8) Ad[gr * 4 + (l15 - 4)] = av;
  }
}

// ---------------- fused softmax + aggregation (wave per node, 8-deep MLP) --------
template <bool OUTFP32>
__global__ __launch_bounds__(256) void agg_kernel(const uint32* __restrict__ H16, const float* __restrict__ As,
                                                  const float* __restrict__ Ad, const int* __restrict__ row_start,
                                                  const int* __restrict__ csr, const float* __restrict__ bias,
                                                  void* __restrict__ outv, int n) {
  int wid = (blockIdx.x * 256 + threadIdx.x) >> 6;
  int lane = threadIdx.x & 63;
  if (wid >= n) return;
  int base = row_start[wid];
  int deg = row_start[wid + 1] - base;
  if (deg < 0) deg = 0;
  int hsel = lane >> 4;
  float adsel = Ad[wid * 4 + hsel];
  float pself = __expf(leaky(As[wid * 4 + hsel] + adsel));
  float2 hv = unpack_bf16(H16[(size_t)wid * 64 + lane]);
  float den = pself;
  float acc0 = pself * hv.x, acc1 = pself * hv.y;
  for (int chunk = 0; chunk < deg; chunk += 64) {
    int j = chunk + lane;
    int smine = (j < deg) ? clampi(csr[base + j], 0, n - 1) : 0;
    int cnt_ = deg - chunk; if (cnt_ > 64) cnt_ = 64;
    float pm[4];
#pragma unroll
    for (int k = 0; k < 4; ++k) {
      pm[k] = 0.f;
      if (k * 16 < cnt_) {
        int slot = k * 16 + (lane & 15);
        int sk = __shfl(smine, slot);
        float e = As[sk * 4 + hsel];
        pm[k] = (slot < cnt_) ? __expf(leaky(e + adsel)) : 0.f;
      }
    }
#pragma unroll
    for (int k = 0; k < 4; ++k) {
      if (k * 16 >= cnt_) break;
#pragma unroll
      for (int b = 0; b < 2; ++b) {
        int u0 = k * 16 + b * 8;
        if (u0 >= cnt_) break;
        int ss[8];
        float aw[8];
        float2 h2[8];
#pragma unroll
        for (int i = 0; i < 8; ++i) {
          int u = u0 + i;
          int sv = __shfl(smine, u);
          float av = __shfl(pm[k], (lane & 48) + (u & 15));
          ss[i] = (u < cnt_) ? sv : 0;
          aw[i] = (u < cnt_) ? av : 0.f;
        }
#pragma unroll
        for (int i = 0; i < 8; ++i) h2[i] = unpack_bf16(H16[(size_t)((uint32)ss[i] * 64 + lane)]);
#pragma unroll
        for (int i = 0; i < 8; ++i) {
          den += aw[i];
          acc0 += aw[i] * h2[i].x;
          acc1 += aw[i] * h2[i].y;
        }
      }
    }
  }
  float inv = 1.f / den;
  float2 bv = *(const float2*)&bias[2 * lane];
  float r0v = fmaxf(acc0 * inv + bv.x, 0.f);
  float r1v = fmaxf(acc1 * inv + bv.y, 0.f);
  if constexpr (OUTFP32) {
    ((float2*)outv)[(size_t)wid * 64 + lane] = make_float2(r0v, r1v);
  } else {
    ((uint32*)outv)[(size_t)wid * 64 + lane] = pack_bf16(r0v, r1v);
  }
}

// ---------------- pooling ----------------
__global__ __launch_bounds__(128) void pool_kernel(const float* __restrict__ X, const int* __restrict__ batch,
                                                   float* __restrict__ pooled, int n, int G) {
  int c = threadIdx.x;
  int n0 = blockIdx.x * 64;
  if (n0 >= n) return;
  int end = n0 + 64 < n ? n0 + 64 : n;
  int curg = clampi(batch[n0], 0, G - 1);
  float acc = 0.f;
  for (int i = n0; i < end; ++i) {
    int g = clampi(batch[i], 0, G - 1);
    if (g != curg) {
      atomicAdd(&pooled[curg * 128 + c], acc);
      acc = 0.f;
      curg = g;
    }
    acc += X[(size_t)i * 128 + c];
  }
  atomicAdd(&pooled[curg * 128 + c], acc);
}

__global__ __launch_bounds__(64) void logits_kernel(const float* __restrict__ pooled, const float* __restrict__ Wh,
                                                    const float* __restrict__ bh, float* __restrict__ out) {
  int g = blockIdx.x, lane = threadIdx.x;
  float p0 = pooled[g * 128 + lane];
  float p1 = pooled[g * 128 + lane + 64];
  for (int o = 0; o < 10; ++o) {
    float v = p0 * Wh[lane * 10 + o] + p1 * Wh[(lane + 64) * 10 + o];
#pragma unroll
    for (int off = 32; off >= 1; off >>= 1) v += __shfl_xor(v, off);
    if (lane == 0) out[g * 10 + o] = v + bh[o];
  }
}

extern "C" void kernel_launch(void* const* d_in, const int* in_sizes, int n_in,
                              void* d_out, int out_size, void* d_ws, size_t ws_size,
                              hipStream_t stream) {
  const float *x, *Wl[3], *asr[3], *adr[3], *bias[3], *Wh, *bh;
  const int *edge_index, *batch;
  long long E_ll;
  if (n_in >= 17) {
    x = (const float*)d_in[0];
    for (int l = 0; l < 3; ++l) {
      Wl[l] = (const float*)d_in[1 + l];
      asr[l] = (const float*)d_in[4 + l];
      adr[l] = (const float*)d_in[7 + l];
      bias[l] = (const float*)d_in[10 + l];
    }
    Wh = (const float*)d_in[13];
    bh = (const float*)d_in[14];
    edge_index = (const int*)d_in[15];
    batch = (const int*)d_in[16];
    E_ll = (long long)in_sizes[15] / 2;
  } else if (n_in >= 9) {
    x = (const float*)d_in[0];
    const float* Wc = (const float*)d_in[1];
    const float* ac = (const float*)d_in[2];
    const float* dc = (const float*)d_in[3];
    const float* bc = (const float*)d_in[4];
    for (int l = 0; l < 3; ++l) {
      Wl[l] = Wc + (size_t)l * HC * HC;
      asr[l] = ac + (size_t)l * HC;
      adr[l] = dc + (size_t)l * HC;
      bias[l] = bc + (size_t)l * HC;
    }
    Wh = (const float*)d_in[5];
    bh = (const float*)d_in[6];
    edge_index = (const int*)d_in[7];
    batch = (const int*)d_in[8];
    E_ll = (long long)in_sizes[7] / 2;
  } else {
    zero_kernel<<<(out_size + 255) / 256, 256, 0, stream>>>((int*)d_out, out_size);
    return;
  }
  int N = in_sizes[0] / HC;
  int G = out_size / 10;
  if (N <= 0 || G <= 0 || E_ll <= 0 || E_ll > (1LL << 30)) {
    zero_kernel<<<(out_size + 255) / 256, 256, 0, stream>>>((int*)d_out, out_size);
    return;
  }
  int E = (int)E_ll;
  int NBKT = (N + 255) >> 8;
  int NC = NBKT * NSUB;

  char* w = (char*)d_ws;
  size_t off = 0;
  auto take = [&](size_t bytes) -> char* {
    char* p = w + off;
    off = (off + bytes + 511) & ~(size_t)511;
    return p;
  };
  uint32* H16 = (uint32*)take((size_t)N * 64 * 4);
  uint32* X16 = (uint32*)take((size_t)N * 64 * 4);
  float* bufQ = (float*)take((size_t)N * HC * 4);   // layer-2 fp32 output
  uint32* Xa = (uint32*)bufQ;                        // aliased: bf16 x (consumed before bufQ written)
  float* As = (float*)take((size_t)N * NHEAD * 4);
  float* Ad = (float*)take((size_t)N * NHEAD * 4);
  int* row_start = (int*)take((size_t)(N + 1) * 4);
  int* csr = (int*)take((size_t)E * 4);
  int2* ebuf = (int2*)take((size_t)E * 8);
  int* bcnt = (int*)take((size_t)NC * 4);
  int* bbase = (int*)take((size_t)NC * 4);
  int* bcur = (int*)take((size_t)NC * 4);
  float* pooled = (float*)take((size_t)G * HC * 4);
  unsigned short* wt16 = (unsigned short*)take((size_t)3 * WT_STRIDE * 2);

  if (off > ws_size) {
    zero_kernel<<<(out_size + 255) / 256, 256, 0, stream>>>((int*)d_out, out_size);
    return;
  }

  const int* esrc = edge_index;
  const int* edst = edge_index + E;

  long long n64 = (long long)N * 64;
  long long prep_items = n64 + 3 * 16384 + 3 * 2048 + NC + (long long)G * 128;
  prep_kernel<<<(int)((prep_items + 255) / 256), 256, 0, stream>>>(
      x, Wl[0], Wl[1], Wl[2], asr[0], asr[1], asr[2], adr[0], adr[1], adr[2], Xa, wt16, bcnt, pooled, n64, NC, G);

  bincnt_kernel<<<(E + 255) / 256, 256, 0, stream>>>(edst, bcnt, E, N);
  bscan_kernel<<<1, 256, 0, stream>>>(bcnt, bbase, bcur, NC);
  binscatter_kernel<<<(E + 255) / 256, 256, 0, stream>>>(esrc, edst, bcur, ebuf, E, N);
  bucket_finalize<<<NBKT, 256, 0, stream>>>(ebuf, bbase, row_start, csr, NBKT, E, N);

  int gemm_grid = (N + 63) / 64;
  int agg_grid = (N + 3) / 4;

  // layer 0
  gemm_mfma<<<gemm_grid, 256, 0, stream>>>(Xa, wt16, H16, As, Ad, N);
  agg_kernel<false><<<agg_grid, 256, 0, stream>>>(H16, As, Ad, row_start, csr, bias[0], X16, N);
  // layer 1
  gemm_mfma<<<gemm_grid, 256, 0, stream>>>(X16, wt16 + WT_STRIDE, H16, As, Ad, N);
  agg_kernel<false><<<agg_grid, 256, 0, stream>>>(H16, As, Ad, row_start, csr, bias[1], X16, N);
  // layer 2 (agg -> fp32 bufQ; Xa no longer needed)
  gemm_mfma<<<gemm_grid, 256, 0, stream>>>(X16, wt16 + 2 * WT_STRIDE, H16, As, Ad, N);
  agg_kernel<true><<<agg_grid, 256, 0, stream>>>(H16, As, Ad, row_start, csr, bias[2], bufQ, N);

  pool_kernel<<<(N + 63) / 64, 128, 0, stream>>>(bufQ, batch, pooled, N, G);
  logits_kernel<<<G, 64, 0, stream>>>(pooled, Wh, bh, (float*)d_out);
}

// Round 15
// 277.855 us; speedup vs baseline: 1.9257x; 1.9257x over previous
//
#include <hip/hip_runtime.h>
#include <hip/hip_bf16.h>

#define HC 128
#define NHEAD 4
#define NEG 0.2f
#define CHUNK 4096  // edges per block in staged binning

typedef unsigned int uint32;
typedef __attribute__((ext_vector_type(8))) short short8v;
typedef __attribute__((ext_vector_type(4))) float f32x4;

__device__ __forceinline__ float leaky(float v) { return v > 0.f ? v : NEG * v; }
__device__ __forceinline__ int clampi(int v, int lo, int hi) { return v < lo ? lo : (v > hi ? hi : v); }

__device__ __forceinline__ uint32 pack_bf16(float lo, float hi) {
  uint32 a = __float_as_uint(lo);
  uint32 b = __float_as_uint(hi);
  a = (a + 0x7FFFu + ((a >> 16) & 1u)) >> 16;
  b = (b + 0x7FFFu + ((b >> 16) & 1u)) & 0xFFFF0000u;
  return a | b;
}
__device__ __forceinline__ unsigned short bf16_1(float v) {
  uint32 a = __float_as_uint(v);
  return (unsigned short)((a + 0x7FFFu + ((a >> 16) & 1u)) >> 16);
}
__device__ __forceinline__ float2 unpack_bf16(uint32 u) {
  return make_float2(__uint_as_float(u << 16), __uint_as_float(u & 0xFFFF0000u));
}
__device__ __forceinline__ short8v as_s8(uint4 u) {
  union { uint4 a; short8v b; } c; c.a = u; return c.b;
}

#define WT_STRIDE 18432  // 144*128

// ---------------- utility ----------------
__global__ __launch_bounds__(256) void zero_kernel(int* __restrict__ p, int n) {
  int i = blockIdx.x * 256 + threadIdx.x;
  int stride = gridDim.x * 256;
  for (; i < n; i += stride) p[i] = 0;
}

// ================= staged CSR build (NBKT <= 256 path) =================
// K1: global bucket histogram via LDS privatization
__global__ __launch_bounds__(256) void bincnt_lds(const int* __restrict__ dst, int* __restrict__ bcnt, int E, int n) {
  __shared__ int h[256];
  int t = threadIdx.x;
  h[t] = 0;
  __syncthreads();
  int e0 = blockIdx.x * CHUNK;
  int e1 = e0 + CHUNK < E ? e0 + CHUNK : E;
  for (int i = e0 + t; i < e1; i += 256) {
    int d = clampi(dst[i], 0, n - 1);
    atomicAdd(&h[d >> 8], 1);
  }
  __syncthreads();
  if (h[t] > 0) atomicAdd(&bcnt[t], h[t]);
}

// K2: 1-block exclusive scan of NBKT bucket counts -> bbase, bcur
__global__ __launch_bounds__(256) void bscan_kernel(const int* __restrict__ bcnt, int* __restrict__ bbase,
                                                    int* __restrict__ bcur, int NBKT) {
  __shared__ int part[256];
  int t = threadIdx.x;
  int c = (t < NBKT) ? bcnt[t] : 0;
  part[t] = c;
  __syncthreads();
  for (int off = 1; off < 256; off <<= 1) {
    int v = (t >= off) ? part[t - off] : 0;
    __syncthreads();
    part[t] += v;
    __syncthreads();
  }
  int excl = part[t] - c;
  if (t < NBKT) {
    bbase[t] = excl;
    bcur[t] = excl;
  }
}

// K3: staged scatter: per-block LDS count -> reserve contiguous range per bucket
// -> place. Each block writes only its own exclusive ebuf ranges (no cross-block
// line sharing -> L2 merges; ~196 global atomics per block).
__global__ __launch_bounds__(256) void binscatter_staged(const int* __restrict__ src, const int* __restrict__ dst,
                                                         int* __restrict__ bcur, int2* __restrict__ ebuf, int E, int n) {
  __shared__ int lcnt[256];
  __shared__ int lbase[256];
  int t = threadIdx.x;
  lcnt[t] = 0;
  __syncthreads();
  int e0 = blockIdx.x * CHUNK;
  int e1 = e0 + CHUNK < E ? e0 + CHUNK : E;
  for (int i = e0 + t; i < e1; i += 256) {
    int d = clampi(dst[i], 0, n - 1);
    atomicAdd(&lcnt[d >> 8], 1);
  }
  __syncthreads();
  int myc = lcnt[t];
  lbase[t] = (myc > 0) ? atomicAdd(&bcur[t], myc) : 0;
  __syncthreads();
  lcnt[t] = 0;
  __syncthreads();
  for (int i = e0 + t; i < e1; i += 256) {
    int d = clampi(dst[i], 0, n - 1);
    int s = clampi(src[i], 0, n - 1);
    int b = d >> 8;
    int pos = atomicAdd(&lcnt[b], 1);
    int p = lbase[b] + pos;
    if (p >= 0 && p < E) ebuf[p] = make_int2(s, d);
  }
}

// K4: per-bucket (256 dsts): LDS histogram + scan -> row_start, place csr
__global__ __launch_bounds__(256) void bucket_finalize(const int2* __restrict__ ebuf, const int* __restrict__ bbase,
                                                       int* __restrict__ row_start, int* __restrict__ csr,
                                                       int NBKT, int E, int n) {
  __shared__ int cnt[256];
  __shared__ int part[256];
  __shared__ int cur[256];
  int b = blockIdx.x;
  int t = threadIdx.x;
  int start = bbase[b];
  int end = (b == NBKT - 1) ? E : bbase[b + 1];
  int d0 = b << 8;
  int ndst = n - d0; if (ndst > 256) ndst = 256;
  cnt[t] = 0;
  __syncthreads();
  for (int i = start + t; i < end; i += 256) {
    int d = ebuf[i].y - d0;
    if (d >= 0 && d < 256) atomicAdd(&cnt[d], 1);
  }
  __syncthreads();
  int c = cnt[t];
  part[t] = c;
  __syncthreads();
  for (int off = 1; off < 256; off <<= 1) {
    int v = (t >= off) ? part[t - off] : 0;
    __syncthreads();
    part[t] += v;
    __syncthreads();
  }
  int excl = part[t] - c;
  if (t < ndst) row_start[d0 + t] = start + excl;
  if (b == NBKT - 1 && t == 0) row_start[n] = E;
  cur[t] = start + excl;
  __syncthreads();
  for (int i = start + t; i < end; i += 256) {
    int2 pr = ebuf[i];
    int d = pr.y - d0;
    if (d >= 0 && d < 256) {
      int p = atomicAdd(&cur[d], 1);
      if (p >= 0 && p < E) csr[p] = pr.x;
    }
  }
}

// ================= fallback CSR build (NBKT > 256; not hit at N=50K) ============
__global__ __launch_bounds__(256) void hist_kernel(const int* __restrict__ dst, int* __restrict__ cnt, int E, int n) {
  int e = blockIdx.x * 256 + threadIdx.x;
  if (e < E) atomicAdd(&cnt[clampi(dst[e], 0, n - 1)], 1);
}
__global__ __launch_bounds__(256) void scan_pass1(const int* __restrict__ cnt, int* __restrict__ blocksum, int n) {
  __shared__ int red[256];
  int t = threadIdx.x;
  int i = blockIdx.x * 256 + t;
  red[t] = i < n ? cnt[i] : 0;
  __syncthreads();
  for (int off = 128; off >= 1; off >>= 1) {
    if (t < off) red[t] += red[t + off];
    __syncthreads();
  }
  if (t == 0) blocksum[blockIdx.x] = red[0];
}
__global__ __launch_bounds__(256) void scan_pass2(const int* __restrict__ blocksum, int* __restrict__ blockpre,
                                                  int* __restrict__ row_start, int NB, int n) {
  __shared__ int part[256];
  int t = threadIdx.x;
  int chunk = (NB + 255) >> 8;
  int lo = t * chunk; if (lo > NB) lo = NB;
  int hi = lo + chunk; if (hi > NB) hi = NB;
  int s = 0;
  for (int i = lo; i < hi; ++i) s += blocksum[i];
  part[t] = s;
  __syncthreads();
  for (int off = 1; off < 256; off <<= 1) {
    int v = (t >= off) ? part[t - off] : 0;
    __syncthreads();
    part[t] += v;
    __syncthreads();
  }
  int run = part[t] - s;
  for (int i = lo; i < hi; ++i) {
    blockpre[i] = run;
    run += blocksum[i];
  }
  if (t == 255) row_start[n] = part[255];
}
__global__ __launch_bounds__(256) void scan_pass3(const int* __restrict__ cnt, const int* __restrict__ blockpre,
                                                  int* __restrict__ row_start, int* __restrict__ cursor, int n) {
  __shared__ int part[256];
  int t = threadIdx.x;
  int i = blockIdx.x * 256 + t;
  int c = i < n ? cnt[i] : 0;
  part[t] = c;
  __syncthreads();
  for (int off = 1; off < 256; off <<= 1) {
    int v = (t >= off) ? part[t - off] : 0;
    __syncthreads();
    part[t] += v;
    __syncthreads();
  }
  int excl = part[t] - c;
  if (i < n) {
    int b = blockpre[blockIdx.x] + excl;
    row_start[i] = b;
    cursor[i] = b;
  }
}
__global__ __launch_bounds__(256) void scatter_kernel(const int* __restrict__ src, const int* __restrict__ dst,
                                                      int* __restrict__ cursor, int* __restrict__ csr, int E, int n) {
  int e = blockIdx.x * 256 + threadIdx.x;
  if (e < E) {
    int d = clampi(dst[e], 0, n - 1);
    int s = clampi(src[e], 0, n - 1);
    int p = atomicAdd(&cursor[d], 1);
    if (p >= 0 && p < E) csr[p] = s;
  }
}

// ---------------- fused prep: xprep + W transpose + fused-alpha cols + zero-init --
__global__ __launch_bounds__(256) void prep_kernel(const float* __restrict__ x, const float* __restrict__ W0,
                                                   const float* __restrict__ W1, const float* __restrict__ W2,
                                                   const float* __restrict__ as0, const float* __restrict__ as1,
                                                   const float* __restrict__ as2, const float* __restrict__ ad0,
                                                   const float* __restrict__ ad1, const float* __restrict__ ad2,
                                                   uint32* __restrict__ X16, unsigned short* __restrict__ wt,
                                                   int* __restrict__ bcnt, float* __restrict__ pooled,
                                                   long long n64, int NC, int Gp) {
  long long id = (long long)blockIdx.x * 256 + threadIdx.x;
  if (id < n64) {
    float2 v = *(const float2*)&x[id * 2];
    X16[id] = pack_bf16(v.x, v.y);
    return;
  }
  long long id2l = id - n64;
  if (id2l < 3 * 16384) {
    int id2 = (int)id2l;
    int l = id2 >> 14;
    int r = id2 & 16383;
    int k = r >> 7, nc = r & 127;
    const float* W = l == 0 ? W0 : (l == 1 ? W1 : W2);
    wt[(size_t)l * WT_STRIDE + nc * 128 + k] = bf16_1(W[r]);
    return;
  }
  id2l -= 3 * 16384;
  if (id2l < 3 * 2048) {
    int id2 = (int)id2l;
    int l = id2 >> 11;
    int r = id2 & 2047;
    int col8 = r >> 7, k = r & 127;
    const float* W = l == 0 ? W0 : (l == 1 ? W1 : W2);
    unsigned short outv = 0;
    if (col8 < 8) {
      int h = col8 & 3;
      const float* av = (col8 < 4) ? (l == 0 ? as0 : (l == 1 ? as1 : as2))
                                   : (l == 0 ? ad0 : (l == 1 ? ad1 : ad2));
      float s = 0.f;
      for (int c = 0; c < 32; ++c) s += W[k * 128 + 32 * h + c] * av[32 * h + c];
      outv = bf16_1(s);
    }
    wt[(size_t)l * WT_STRIDE + (128 + col8) * 128 + k] = outv;
    return;
  }
  id2l -= 3 * 2048;
  if (id2l < NC) {
    bcnt[id2l] = 0;
    return;
  }
  id2l -= NC;
  if (id2l < (long long)Gp * 128) pooled[id2l] = 0.f;
}

// ---------------- MFMA GEMM: H = X @ W, As/Ad via fused 9th B-tile --------------
__global__ __launch_bounds__(256) void gemm_mfma(const uint32* __restrict__ X16, const unsigned short* __restrict__ Wt,
                                                 uint32* __restrict__ H16, float* __restrict__ As,
                                                 float* __restrict__ Ad, int n) {
  int t = threadIdx.x;
  int wave = t >> 6, lane = t & 63;
  int l15 = lane & 15, lg = lane >> 4;
  int row0 = blockIdx.x * 64 + wave * 16;
  int arow = row0 + l15;
  if (arow >= n) arow = n - 1;
  const uint4* xr = (const uint4*)(X16 + (size_t)arow * 64);
  uint4 a[4];
#pragma unroll
  for (int kc = 0; kc < 4; ++kc) a[kc] = xr[kc * 4 + lg];
  f32x4 acc[9];
#pragma unroll
  for (int nb = 0; nb < 9; ++nb) acc[nb] = (f32x4){0.f, 0.f, 0.f, 0.f};
#pragma unroll
  for (int kc = 0; kc < 4; ++kc) {
    uint4 b[9];
#pragma unroll
    for (int nb = 0; nb < 9; ++nb) {
      int ncol = nb * 16 + l15;
      b[nb] = *(const uint4*)(Wt + (size_t)ncol * 128 + kc * 32 + lg * 8);
    }
#pragma unroll
    for (int nb = 0; nb < 9; ++nb)
      acc[nb] = __builtin_amdgcn_mfma_f32_16x16x32_bf16(as_s8(a[kc]), as_s8(b[nb]), acc[nb], 0, 0, 0);
  }
#pragma unroll
  for (int r = 0; r < 4; ++r) {
    int gr = row0 + lg * 4 + r;
    bool ok = gr < n;
#pragma unroll
    for (int nb = 0; nb < 8; ++nb) {
      float mine = acc[nb][r];
      float other = __shfl_xor(mine, 1);
      if (ok && (lane & 1) == 0) H16[(size_t)gr * 64 + nb * 8 + (l15 >> 1)] = pack_bf16(mine, other);
    }
    float av = acc[8][r];
    if (ok && l15 < 4) As[gr * 4 + l15] = av;
    if (ok && l15 >= 4 && l15 < 8) Ad[gr * 4 + (l15 - 4)] = av;
  }
}

// ---------------- fused softmax + aggregation (wave per node, 8-deep MLP) --------
template <bool OUTFP32>
__global__ __launch_bounds__(256) void agg_kernel(const uint32* __restrict__ H16, const float* __restrict__ As,
                                                  const float* __restrict__ Ad, const int* __restrict__ row_start,
                                                  const int* __restrict__ csr, const float* __restrict__ bias,
                                                  void* __restrict__ outv, int n) {
  int wid = (blockIdx.x * 256 + threadIdx.x) >> 6;
  int lane = threadIdx.x & 63;
  if (wid >= n) return;
  int base = row_start[wid];
  int deg = row_start[wid + 1] - base;
  if (deg < 0) deg = 0;
  int hsel = lane >> 4;
  float adsel = Ad[wid * 4 + hsel];
  float pself = __expf(leaky(As[wid * 4 + hsel] + adsel));
  float2 hv = unpack_bf16(H16[(size_t)wid * 64 + lane]);
  float den = pself;
  float acc0 = pself * hv.x, acc1 = pself * hv.y;
  for (int chunk = 0; chunk < deg; chunk += 64) {
    int j = chunk + lane;
    int smine = (j < deg) ? clampi(csr[base + j], 0, n - 1) : 0;
    int cnt_ = deg - chunk; if (cnt_ > 64) cnt_ = 64;
    float pm[4];
#pragma unroll
    for (int k = 0; k < 4; ++k) {
      pm[k] = 0.f;
      if (k * 16 < cnt_) {
        int slot = k * 16 + (lane & 15);
        int sk = __shfl(smine, slot);
        float e = As[sk * 4 + hsel];
        pm[k] = (slot < cnt_) ? __expf(leaky(e + adsel)) : 0.f;
      }
    }
#pragma unroll
    for (int k = 0; k < 4; ++k) {
      if (k * 16 >= cnt_) break;
#pragma unroll
      for (int b = 0; b < 2; ++b) {
        int u0 = k * 16 + b * 8;
        if (u0 >= cnt_) break;
        int ss[8];
        float aw[8];
        float2 h2[8];
#pragma unroll
        for (int i = 0; i < 8; ++i) {
          int u = u0 + i;
          int sv = __shfl(smine, u);
          float av = __shfl(pm[k], (lane & 48) + (u & 15));
          ss[i] = (u < cnt_) ? sv : 0;
          aw[i] = (u < cnt_) ? av : 0.f;
        }
#pragma unroll
        for (int i = 0; i < 8; ++i) h2[i] = unpack_bf16(H16[(size_t)((uint32)ss[i] * 64 + lane)]);
#pragma unroll
        for (int i = 0; i < 8; ++i) {
          den += aw[i];
          acc0 += aw[i] * h2[i].x;
          acc1 += aw[i] * h2[i].y;
        }
      }
    }
  }
  float inv = 1.f / den;
  float2 bv = *(const float2*)&bias[2 * lane];
  float r0v = fmaxf(acc0 * inv + bv.x, 0.f);
  float r1v = fmaxf(acc1 * inv + bv.y, 0.f);
  if constexpr (OUTFP32) {
    ((float2*)outv)[(size_t)wid * 64 + lane] = make_float2(r0v, r1v);
  } else {
    ((uint32*)outv)[(size_t)wid * 64 + lane] = pack_bf16(r0v, r1v);
  }
}

// ---------------- pooling ----------------
__global__ __launch_bounds__(128) void pool_kernel(const float* __restrict__ X, const int* __restrict__ batch,
                                                   float* __restrict__ pooled, int n, int G) {
  int c = threadIdx.x;
  int n0 = blockIdx.x * 64;
  if (n0 >= n) return;
  int end = n0 + 64 < n ? n0 + 64 : n;
  int curg = clampi(batch[n0], 0, G - 1);
  float acc = 0.f;
  for (int i = n0; i < end; ++i) {
    int g = clampi(batch[i], 0, G - 1);
    if (g != curg) {
      atomicAdd(&pooled[curg * 128 + c], acc);
      acc = 0.f;
      curg = g;
    }
    acc += X[(size_t)i * 128 + c];
  }
  atomicAdd(&pooled[curg * 128 + c], acc);
}

__global__ __launch_bounds__(64) void logits_kernel(const float* __restrict__ pooled, const float* __restrict__ Wh,
                                                    const float* __restrict__ bh, float* __restrict__ out) {
  int g = blockIdx.x, lane = threadIdx.x;
  float p0 = pooled[g * 128 + lane];
  float p1 = pooled[g * 128 + lane + 64];
  for (int o = 0; o < 10; ++o) {
    float v = p0 * Wh[lane * 10 + o] + p1 * Wh[(lane + 64) * 10 + o];
#pragma unroll
    for (int off = 32; off >= 1; off >>= 1) v += __shfl_xor(v, off);
    if (lane == 0) out[g * 10 + o] = v + bh[o];
  }
}

extern "C" void kernel_launch(void* const* d_in, const int* in_sizes, int n_in,
                              void* d_out, int out_size, void* d_ws, size_t ws_size,
                              hipStream_t stream) {
  const float *x, *Wl[3], *asr[3], *adr[3], *bias[3], *Wh, *bh;
  const int *edge_index, *batch;
  long long E_ll;
  if (n_in >= 17) {
    x = (const float*)d_in[0];
    for (int l = 0; l < 3; ++l) {
      Wl[l] = (const float*)d_in[1 + l];
      asr[l] = (const float*)d_in[4 + l];
      adr[l] = (const float*)d_in[7 + l];
      bias[l] = (const float*)d_in[10 + l];
    }
    Wh = (const float*)d_in[13];
    bh = (const float*)d_in[14];
    edge_index = (const int*)d_in[15];
    batch = (const int*)d_in[16];
    E_ll = (long long)in_sizes[15] / 2;
  } else if (n_in >= 9) {
    x = (const float*)d_in[0];
    const float* Wc = (const float*)d_in[1];
    const float* ac = (const float*)d_in[2];
    const float* dc = (const float*)d_in[3];
    const float* bc = (const float*)d_in[4];
    for (int l = 0; l < 3; ++l) {
      Wl[l] = Wc + (size_t)l * HC * HC;
      asr[l] = ac + (size_t)l * HC;
      adr[l] = dc + (size_t)l * HC;
      bias[l] = bc + (size_t)l * HC;
    }
    Wh = (const float*)d_in[5];
    bh = (const float*)d_in[6];
    edge_index = (const int*)d_in[7];
    batch = (const int*)d_in[8];
    E_ll = (long long)in_sizes[7] / 2;
  } else {
    zero_kernel<<<(out_size + 255) / 256, 256, 0, stream>>>((int*)d_out, out_size);
    return;
  }
  int N = in_sizes[0] / HC;
  int G = out_size / 10;
  if (N <= 0 || G <= 0 || E_ll <= 0 || E_ll > (1LL << 30)) {
    zero_kernel<<<(out_size + 255) / 256, 256, 0, stream>>>((int*)d_out, out_size);
    return;
  }
  int E = (int)E_ll;
  int NBKT = (N + 255) >> 8;
  int NB = (N + 255) / 256;
  bool staged = (NBKT <= 256);

  char* w = (char*)d_ws;
  size_t off = 0;
  auto take = [&](size_t bytes) -> char* {
    char* p = w + off;
    off = (off + bytes + 511) & ~(size_t)511;
    return p;
  };
  uint32* H16 = (uint32*)take((size_t)N * 64 * 4);
  uint32* X16 = (uint32*)take((size_t)N * 64 * 4);
  float* bufQ = (float*)take((size_t)N * HC * 4);   // layer-2 fp32 output
  uint32* Xa = (uint32*)bufQ;                        // aliased: bf16 x (consumed before bufQ written)
  float* As = (float*)take((size_t)N * NHEAD * 4);
  float* Ad = (float*)take((size_t)N * NHEAD * 4);
  int* row_start = (int*)take((size_t)(N + 1) * 4);
  int* csr = (int*)take((size_t)E * 4);
  int2* ebuf = (int2*)take((size_t)E * 8);
  int* bcnt = (int*)take(256 * 4);
  int* bbase = (int*)take(256 * 4);
  int* bcur = (int*)take(256 * 4);
  int* cnt = (int*)take((size_t)N * 4);       // fallback
  int* cursor = (int*)take((size_t)N * 4);    // fallback
  int* blocksum = (int*)take((size_t)NB * 4); // fallback
  int* blockpre = (int*)take((size_t)NB * 4); // fallback
  float* pooled = (float*)take((size_t)G * HC * 4);
  unsigned short* wt16 = (unsigned short*)take((size_t)3 * WT_STRIDE * 2);

  if (off > ws_size) {
    zero_kernel<<<(out_size + 255) / 256, 256, 0, stream>>>((int*)d_out, out_size);
    return;
  }

  const int* esrc = edge_index;
  const int* edst = edge_index + E;

  long long n64 = (long long)N * 64;
  long long prep_items = n64 + 3 * 16384 + 3 * 2048 + 256 + (long long)G * 128;
  prep_kernel<<<(int)((prep_items + 255) / 256), 256, 0, stream>>>(
      x, Wl[0], Wl[1], Wl[2], asr[0], asr[1], asr[2], adr[0], adr[1], adr[2], Xa, wt16, bcnt, pooled, n64, 256, G);

  int echunks = (E + CHUNK - 1) / CHUNK;
  if (staged) {
    bincnt_lds<<<echunks, 256, 0, stream>>>(edst, bcnt, E, N);
    bscan_kernel<<<1, 256, 0, stream>>>(bcnt, bbase, bcur, NBKT);
    binscatter_staged<<<echunks, 256, 0, stream>>>(esrc, edst, bcur, ebuf, E, N);
    bucket_finalize<<<NBKT, 256, 0, stream>>>(ebuf, bbase, row_start, csr, NBKT, E, N);
  } else {
    zero_kernel<<<(N + 255) / 256, 256, 0, stream>>>(cnt, N);
    hist_kernel<<<(E + 255) / 256, 256, 0, stream>>>(edst, cnt, E, N);
    scan_pass1<<<NB, 256, 0, stream>>>(cnt, blocksum, N);
    scan_pass2<<<1, 256, 0, stream>>>(blocksum, blockpre, row_start, NB, N);
    scan_pass3<<<NB, 256, 0, stream>>>(cnt, blockpre, row_start, cursor, N);
    scatter_kernel<<<(E + 255) / 256, 256, 0, stream>>>(esrc, edst, cursor, csr, E, N);
  }

  int gemm_grid = (N + 63) / 64;
  int agg_grid = (N + 3) / 4;

  // layer 0
  gemm_mfma<<<gemm_grid, 256, 0, stream>>>(Xa, wt16, H16, As, Ad, N);
  agg_kernel<false><<<agg_grid, 256, 0, stream>>>(H16, As, Ad, row_start, csr, bias[0], X16, N);
  // layer 1
  gemm_mfma<<<gemm_grid, 256, 0, stream>>>(X16, wt16 + WT_STRIDE, H16, As, Ad, N);
  agg_kernel<false><<<agg_grid, 256, 0, stream>>>(H16, As, Ad, row_start, csr, bias[1], X16, N);
  // layer 2 (agg -> fp32 bufQ; Xa no longer needed)
  gemm_mfma<<<gemm_grid, 256, 0, stream>>>(X16, wt16 + 2 * WT_STRIDE, H16, As, Ad, N);
  agg_kernel<true><<<agg_grid, 256, 0, stream>>>(H16, As, Ad, row_start, csr, bias[2], bufQ, N);

  pool_kernel<<<(N + 63) / 64, 128, 0, stream>>>(bufQ, batch, pooled, N, G);
  logits_kernel<<<G, 64, 0, stream>>>(pooled, Wh, bh, (float*)d_out);
}

// Round 16
// 261.507 us; speedup vs baseline: 2.0461x; 1.0625x over previous
//
#include <hip/hip_runtime.h>
#include <hip/hip_bf16.h>

#define HC 128
#define NHEAD 4
#define NEG 0.2f
#define CHUNK 4096  // edges per block in staged binning

typedef unsigned int uint32;
typedef __attribute__((ext_vector_type(8))) short short8v;
typedef __attribute__((ext_vector_type(4))) float f32x4;

__device__ __forceinline__ float leaky(float v) { return v > 0.f ? v : NEG * v; }
__device__ __forceinline__ int clampi(int v, int lo, int hi) { return v < lo ? lo : (v > hi ? hi : v); }

__device__ __forceinline__ uint32 pack_bf16(float lo, float hi) {
  uint32 a = __float_as_uint(lo);
  uint32 b = __float_as_uint(hi);
  a = (a + 0x7FFFu + ((a >> 16) & 1u)) >> 16;
  b = (b + 0x7FFFu + ((b >> 16) & 1u)) & 0xFFFF0000u;
  return a | b;
}
__device__ __forceinline__ unsigned short bf16_1(float v) {
  uint32 a = __float_as_uint(v);
  return (unsigned short)((a + 0x7FFFu + ((a >> 16) & 1u)) >> 16);
}
__device__ __forceinline__ float2 unpack_bf16(uint32 u) {
  return make_float2(__uint_as_float(u << 16), __uint_as_float(u & 0xFFFF0000u));
}
__device__ __forceinline__ short8v as_s8(uint4 u) {
  union { uint4 a; short8v b; } c; c.a = u; return c.b;
}

#define WT_STRIDE 18432  // 144*128

// ---------------- utility ----------------
__global__ __launch_bounds__(256) void zero_kernel(int* __restrict__ p, int n) {
  int i = blockIdx.x * 256 + threadIdx.x;
  int stride = gridDim.x * 256;
  for (; i < n; i += stride) p[i] = 0;
}

// ================= staged CSR build (NBKT <= 256 path) =================
__global__ __launch_bounds__(256) void bincnt_lds(const int* __restrict__ dst, int* __restrict__ bcnt, int E, int n) {
  __shared__ int h[256];
  int t = threadIdx.x;
  h[t] = 0;
  __syncthreads();
  int e0 = blockIdx.x * CHUNK;
  int e1 = e0 + CHUNK < E ? e0 + CHUNK : E;
  for (int i = e0 + t; i < e1; i += 256) {
    int d = clampi(dst[i], 0, n - 1);
    atomicAdd(&h[d >> 8], 1);
  }
  __syncthreads();
  if (h[t] > 0) atomicAdd(&bcnt[t], h[t]);
}

__global__ __launch_bounds__(256) void bscan_kernel(const int* __restrict__ bcnt, int* __restrict__ bbase,
                                                    int* __restrict__ bcur, int NBKT) {
  __shared__ int part[256];
  int t = threadIdx.x;
  int c = (t < NBKT) ? bcnt[t] : 0;
  part[t] = c;
  __syncthreads();
  for (int off = 1; off < 256; off <<= 1) {
    int v = (t >= off) ? part[t - off] : 0;
    __syncthreads();
    part[t] += v;
    __syncthreads();
  }
  int excl = part[t] - c;
  if (t < NBKT) {
    bbase[t] = excl;
    bcur[t] = excl;
  }
}

__global__ __launch_bounds__(256) void binscatter_staged(const int* __restrict__ src, const int* __restrict__ dst,
                                                         int* __restrict__ bcur, int2* __restrict__ ebuf, int E, int n) {
  __shared__ int lcnt[256];
  __shared__ int lbase[256];
  int t = threadIdx.x;
  lcnt[t] = 0;
  __syncthreads();
  int e0 = blockIdx.x * CHUNK;
  int e1 = e0 + CHUNK < E ? e0 + CHUNK : E;
  for (int i = e0 + t; i < e1; i += 256) {
    int d = clampi(dst[i], 0, n - 1);
    atomicAdd(&lcnt[d >> 8], 1);
  }
  __syncthreads();
  int myc = lcnt[t];
  lbase[t] = (myc > 0) ? atomicAdd(&bcur[t], myc) : 0;
  __syncthreads();
  lcnt[t] = 0;
  __syncthreads();
  for (int i = e0 + t; i < e1; i += 256) {
    int d = clampi(dst[i], 0, n - 1);
    int s = clampi(src[i], 0, n - 1);
    int b = d >> 8;
    int pos = atomicAdd(&lcnt[b], 1);
    int p = lbase[b] + pos;
    if (p >= 0 && p < E) ebuf[p] = make_int2(s, d);
  }
}

__global__ __launch_bounds__(256) void bucket_finalize(const int2* __restrict__ ebuf, const int* __restrict__ bbase,
                                                       int* __restrict__ row_start, int* __restrict__ csr,
                                                       int NBKT, int E, int n) {
  __shared__ int cnt[256];
  __shared__ int part[256];
  __shared__ int cur[256];
  int b = blockIdx.x;
  int t = threadIdx.x;
  int start = bbase[b];
  int end = (b == NBKT - 1) ? E : bbase[b + 1];
  int d0 = b << 8;
  int ndst = n - d0; if (ndst > 256) ndst = 256;
  cnt[t] = 0;
  __syncthreads();
  for (int i = start + t; i < end; i += 256) {
    int d = ebuf[i].y - d0;
    if (d >= 0 && d < 256) atomicAdd(&cnt[d], 1);
  }
  __syncthreads();
  int c = cnt[t];
  part[t] = c;
  __syncthreads();
  for (int off = 1; off < 256; off <<= 1) {
    int v = (t >= off) ? part[t - off] : 0;
    __syncthreads();
    part[t] += v;
    __syncthreads();
  }
  int excl = part[t] - c;
  if (t < ndst) row_start[d0 + t] = start + excl;
  if (b == NBKT - 1 && t == 0) row_start[n] = E;
  cur[t] = start + excl;
  __syncthreads();
  for (int i = start + t; i < end; i += 256) {
    int2 pr = ebuf[i];
    int d = pr.y - d0;
    if (d >= 0 && d < 256) {
      int p = atomicAdd(&cur[d], 1);
      if (p >= 0 && p < E) csr[p] = pr.x;
    }
  }
}

// ================= fallback CSR build (NBKT > 256) ============
__global__ __launch_bounds__(256) void hist_kernel(const int* __restrict__ dst, int* __restrict__ cnt, int E, int n) {
  int e = blockIdx.x * 256 + threadIdx.x;
  if (e < E) atomicAdd(&cnt[clampi(dst[e], 0, n - 1)], 1);
}
__global__ __launch_bounds__(256) void scan_pass1(const int* __restrict__ cnt, int* __restrict__ blocksum, int n) {
  __shared__ int red[256];
  int t = threadIdx.x;
  int i = blockIdx.x * 256 + t;
  red[t] = i < n ? cnt[i] : 0;
  __syncthreads();
  for (int off = 128; off >= 1; off >>= 1) {
    if (t < off) red[t] += red[t + off];
    __syncthreads();
  }
  if (t == 0) blocksum[blockIdx.x] = red[0];
}
__global__ __launch_bounds__(256) void scan_pass2(const int* __restrict__ blocksum, int* __restrict__ blockpre,
                                                  int* __restrict__ row_start, int NB, int n) {
  __shared__ int part[256];
  int t = threadIdx.x;
  int chunk = (NB + 255) >> 8;
  int lo = t * chunk; if (lo > NB) lo = NB;
  int hi = lo + chunk; if (hi > NB) hi = NB;
  int s = 0;
  for (int i = lo; i < hi; ++i) s += blocksum[i];
  part[t] = s;
  __syncthreads();
  for (int off = 1; off < 256; off <<= 1) {
    int v = (t >= off) ? part[t - off] : 0;
    __syncthreads();
    part[t] += v;
    __syncthreads();
  }
  int run = part[t] - s;
  for (int i = lo; i < hi; ++i) {
    blockpre[i] = run;
    run += blocksum[i];
  }
  if (t == 255) row_start[n] = part[255];
}
__global__ __launch_bounds__(256) void scan_pass3(const int* __restrict__ cnt, const int* __restrict__ blockpre,
                                                  int* __restrict__ row_start, int* __restrict__ cursor, int n) {
  __shared__ int part[256];
  int t = threadIdx.x;
  int i = blockIdx.x * 256 + t;
  int c = i < n ? cnt[i] : 0;
  part[t] = c;
  __syncthreads();
  for (int off = 1; off < 256; off <<= 1) {
    int v = (t >= off) ? part[t - off] : 0;
    __syncthreads();
    part[t] += v;
    __syncthreads();
  }
  int excl = part[t] - c;
  if (i < n) {
    int b = blockpre[blockIdx.x] + excl;
    row_start[i] = b;
    cursor[i] = b;
  }
}
__global__ __launch_bounds__(256) void scatter_kernel(const int* __restrict__ src, const int* __restrict__ dst,
                                                      int* __restrict__ cursor, int* __restrict__ csr, int E, int n) {
  int e = blockIdx.x * 256 + threadIdx.x;
  if (e < E) {
    int d = clampi(dst[e], 0, n - 1);
    int s = clampi(src[e], 0, n - 1);
    int p = atomicAdd(&cursor[d], 1);
    if (p >= 0 && p < E) csr[p] = s;
  }
}

// ---------------- fused prep: x-pack + Wt + alpha cols + zero bcnt + out=bh ------
__global__ __launch_bounds__(256) void prep_kernel(const float* __restrict__ x, const float* __restrict__ W0,
                                                   const float* __restrict__ W1, const float* __restrict__ W2,
                                                   const float* __restrict__ as0, const float* __restrict__ as1,
                                                   const float* __restrict__ as2, const float* __restrict__ ad0,
                                                   const float* __restrict__ ad1, const float* __restrict__ ad2,
                                                   const float* __restrict__ bh, uint32* __restrict__ X16,
                                                   unsigned short* __restrict__ wt, int* __restrict__ bcnt,
                                                   float* __restrict__ outp, long long n64, int NC, int Gp) {
  long long id = (long long)blockIdx.x * 256 + threadIdx.x;
  if (id < n64) {
    float2 v = *(const float2*)&x[id * 2];
    X16[id] = pack_bf16(v.x, v.y);
    return;
  }
  long long id2l = id - n64;
  if (id2l < 3 * 16384) {
    int id2 = (int)id2l;
    int l = id2 >> 14;
    int r = id2 & 16383;
    int k = r >> 7, nc = r & 127;
    const float* W = l == 0 ? W0 : (l == 1 ? W1 : W2);
    wt[(size_t)l * WT_STRIDE + nc * 128 + k] = bf16_1(W[r]);
    return;
  }
  id2l -= 3 * 16384;
  if (id2l < 3 * 2048) {
    int id2 = (int)id2l;
    int l = id2 >> 11;
    int r = id2 & 2047;
    int col8 = r >> 7, k = r & 127;
    const float* W = l == 0 ? W0 : (l == 1 ? W1 : W2);
    unsigned short outv = 0;
    if (col8 < 8) {
      int h = col8 & 3;
      const float* av = (col8 < 4) ? (l == 0 ? as0 : (l == 1 ? as1 : as2))
                                   : (l == 0 ? ad0 : (l == 1 ? ad1 : ad2));
      float s = 0.f;
      for (int c = 0; c < 32; ++c) s += W[k * 128 + 32 * h + c] * av[32 * h + c];
      outv = bf16_1(s);
    }
    wt[(size_t)l * WT_STRIDE + (128 + col8) * 128 + k] = outv;
    return;
  }
  id2l -= 3 * 2048;
  if (id2l < NC) {
    bcnt[id2l] = 0;
    return;
  }
  id2l -= NC;
  if (id2l < (long long)Gp * 10) outp[id2l] = bh[id2l % 10];
}

// ---------------- MFMA GEMM: column-split 2 waves per 16-row group --------------
// Block = 256 threads = 4 waves = 2 row-groups x 2 col-halves. grid = N/32.
// half 0: nb tiles {0,1,2,3, alpha(col128)}; half 1: {4,5,6,7}.
// D layout (verified m89): col = lane&15, row = 4*(lane>>4)+reg.
__global__ __launch_bounds__(256) void gemm_mfma(const uint32* __restrict__ X16, const unsigned short* __restrict__ Wt,
                                                 uint32* __restrict__ H16, float* __restrict__ As,
                                                 float* __restrict__ Ad, int n) {
  int t = threadIdx.x;
  int wave = t >> 6, lane = t & 63;
  int l15 = lane & 15, lg = lane >> 4;
  int grp = wave >> 1, half = wave & 1;
  int row0 = blockIdx.x * 32 + grp * 16;
  int arow = row0 + l15;
  if (arow >= n) arow = n - 1;
  const uint4* xr = (const uint4*)(X16 + (size_t)arow * 64);
  uint4 a[4];
#pragma unroll
  for (int kc = 0; kc < 4; ++kc) a[kc] = xr[kc * 4 + lg];
  const int NT = half ? 4 : 5;
  f32x4 acc[5];
#pragma unroll
  for (int ti = 0; ti < 5; ++ti) acc[ti] = (f32x4){0.f, 0.f, 0.f, 0.f};
#pragma unroll
  for (int kc = 0; kc < 4; ++kc) {
    uint4 b[5];
#pragma unroll
    for (int ti = 0; ti < 5; ++ti) {
      if (ti < NT) {
        int basecol = half ? (4 + ti) * 16 : (ti < 4 ? ti * 16 : 128);
        b[ti] = *(const uint4*)(Wt + (size_t)(basecol + l15) * 128 + kc * 32 + lg * 8);
      }
    }
#pragma unroll
    for (int ti = 0; ti < 5; ++ti)
      if (ti < NT) acc[ti] = __builtin_amdgcn_mfma_f32_16x16x32_bf16(as_s8(a[kc]), as_s8(b[ti]), acc[ti], 0, 0, 0);
  }
#pragma unroll
  for (int r = 0; r < 4; ++r) {
    int gr = row0 + lg * 4 + r;
    bool ok = gr < n;
#pragma unroll
    for (int ti = 0; ti < 4; ++ti) {
      int nb = half * 4 + ti;
      float mine = acc[ti][r];
      float other = __shfl_xor(mine, 1);
      if (ok && (lane & 1) == 0) H16[(size_t)gr * 64 + nb * 8 + (l15 >> 1)] = pack_bf16(mine, other);
    }
    if (half == 0) {
      float av = acc[4][r];
      if (ok && l15 < 4) As[gr * 4 + l15] = av;
      if (ok && l15 >= 4 && l15 < 8) Ad[gr * 4 + (l15 - 4)] = av;
    }
  }
}

// ---------------- fused softmax + aggregation (wave per node, 8-deep MLP) --------
template <bool OUTFP32>
__global__ __launch_bounds__(256) void agg_kernel(const uint32* __restrict__ H16, const float* __restrict__ As,
                                                  const float* __restrict__ Ad, const int* __restrict__ row_start,
                                                  const int* __restrict__ csr, const float* __restrict__ bias,
                                                  void* __restrict__ outv, int n) {
  int wid = (blockIdx.x * 256 + threadIdx.x) >> 6;
  int lane = threadIdx.x & 63;
  if (wid >= n) return;
  int base = row_start[wid];
  int deg = row_start[wid + 1] - base;
  if (deg < 0) deg = 0;
  int hsel = lane >> 4;
  float adsel = Ad[wid * 4 + hsel];
  float pself = __expf(leaky(As[wid * 4 + hsel] + adsel));
  float2 hv = unpack_bf16(H16[(size_t)wid * 64 + lane]);
  float den = pself;
  float acc0 = pself * hv.x, acc1 = pself * hv.y;
  for (int chunk = 0; chunk < deg; chunk += 64) {
    int j = chunk + lane;
    int smine = (j < deg) ? csr[base + j] : 0;  // csr pre-clamped at build
    int cnt_ = deg - chunk; if (cnt_ > 64) cnt_ = 64;
    float pm[4];
#pragma unroll
    for (int k = 0; k < 4; ++k) {
      pm[k] = 0.f;
      if (k * 16 < cnt_) {
        int slot = k * 16 + (lane & 15);
        int sk = __shfl(smine, slot);
        float e = As[sk * 4 + hsel];
        pm[k] = (slot < cnt_) ? __expf(leaky(e + adsel)) : 0.f;
      }
    }
#pragma unroll
    for (int k = 0; k < 4; ++k) {
      if (k * 16 >= cnt_) break;
#pragma unroll
      for (int b = 0; b < 2; ++b) {
        int u0 = k * 16 + b * 8;
        if (u0 >= cnt_) break;
        int ss[8];
        float aw[8];
        float2 h2[8];
        // masks dropped: pm is 0 exactly when u >= cnt_; smine=0 pads row-0 gather
#pragma unroll
        for (int i = 0; i < 8; ++i) {
          ss[i] = __shfl(smine, u0 + i);
          aw[i] = __shfl(pm[k], (lane & 48) + (b * 8 + i));
        }
#pragma unroll
        for (int i = 0; i < 8; ++i) h2[i] = unpack_bf16(H16[(size_t)((uint32)ss[i] * 64 + lane)]);
#pragma unroll
        for (int i = 0; i < 8; ++i) {
          den += aw[i];
          acc0 += aw[i] * h2[i].x;
          acc1 += aw[i] * h2[i].y;
        }
      }
    }
  }
  float inv = 1.f / den;
  float2 bv = *(const float2*)&bias[2 * lane];
  float r0v = fmaxf(acc0 * inv + bv.x, 0.f);
  float r1v = fmaxf(acc1 * inv + bv.y, 0.f);
  if constexpr (OUTFP32) {
    ((float2*)outv)[(size_t)wid * 64 + lane] = make_float2(r0v, r1v);
  } else {
    ((uint32*)outv)[(size_t)wid * 64 + lane] = pack_bf16(r0v, r1v);
  }
}

// ---------------- fused pooling + logits (batch sorted; run-length flush) --------
// out must be pre-initialized to bh (done in prep).
__global__ __launch_bounds__(128) void pool_logits(const float* __restrict__ X, const int* __restrict__ batch,
                                                   const float* __restrict__ Wh, float* __restrict__ out,
                                                   int n, int G) {
  __shared__ float red[128];
  int c = threadIdx.x;
  int n0 = blockIdx.x * 64;
  if (n0 >= n) return;
  int end = n0 + 64 < n ? n0 + 64 : n;
  int curg = clampi(batch[n0], 0, G - 1);
  float acc = 0.f;
  for (int i = n0; i <= end; ++i) {
    int g = (i < end) ? clampi(batch[i], 0, G - 1) : -1;
    if (g != curg) {
      // flush run (uniform branch)
      red[c] = acc;
      __syncthreads();
      if (c < 10) {
        float s = 0.f;
#pragma unroll 16
        for (int cc = 0; cc < 128; ++cc) s += red[cc] * Wh[cc * 10 + c];
        atomicAdd(&out[curg * 10 + c], s);
      }
      __syncthreads();
      acc = 0.f;
      curg = g;
    }
    if (i < end) acc += X[(size_t)i * 128 + c];
  }
}

extern "C" void kernel_launch(void* const* d_in, const int* in_sizes, int n_in,
                              void* d_out, int out_size, void* d_ws, size_t ws_size,
                              hipStream_t stream) {
  const float *x, *Wl[3], *asr[3], *adr[3], *bias[3], *Wh, *bh;
  const int *edge_index, *batch;
  long long E_ll;
  if (n_in >= 17) {
    x = (const float*)d_in[0];
    for (int l = 0; l < 3; ++l) {
      Wl[l] = (const float*)d_in[1 + l];
      asr[l] = (const float*)d_in[4 + l];
      adr[l] = (const float*)d_in[7 + l];
      bias[l] = (const float*)d_in[10 + l];
    }
    Wh = (const float*)d_in[13];
    bh = (const float*)d_in[14];
    edge_index = (const int*)d_in[15];
    batch = (const int*)d_in[16];
    E_ll = (long long)in_sizes[15] / 2;
  } else if (n_in >= 9) {
    x = (const float*)d_in[0];
    const float* Wc = (const float*)d_in[1];
    const float* ac = (const float*)d_in[2];
    const float* dc = (const float*)d_in[3];
    const float* bc = (const float*)d_in[4];
    for (int l = 0; l < 3; ++l) {
      Wl[l] = Wc + (size_t)l * HC * HC;
      asr[l] = ac + (size_t)l * HC;
      adr[l] = dc + (size_t)l * HC;
      bias[l] = bc + (size_t)l * HC;
    }
    Wh = (const float*)d_in[5];
    bh = (const float*)d_in[6];
    edge_index = (const int*)d_in[7];
    batch = (const int*)d_in[8];
    E_ll = (long long)in_sizes[7] / 2;
  } else {
    zero_kernel<<<(out_size + 255) / 256, 256, 0, stream>>>((int*)d_out, out_size);
    return;
  }
  int N = in_sizes[0] / HC;
  int G = out_size / 10;
  if (N <= 0 || G <= 0 || E_ll <= 0 || E_ll > (1LL << 30)) {
    zero_kernel<<<(out_size + 255) / 256, 256, 0, stream>>>((int*)d_out, out_size);
    return;
  }
  int E = (int)E_ll;
  int NBKT = (N + 255) >> 8;
  int NB = (N + 255) / 256;
  bool staged = (NBKT <= 256);

  char* w = (char*)d_ws;
  size_t off = 0;
  auto take = [&](size_t bytes) -> char* {
    char* p = w + off;
    off = (off + bytes + 511) & ~(size_t)511;
    return p;
  };
  uint32* H16 = (uint32*)take((size_t)N * 64 * 4);
  uint32* X16 = (uint32*)take((size_t)N * 64 * 4);
  float* bufQ = (float*)take((size_t)N * HC * 4);   // layer-2 fp32 output
  uint32* Xa = (uint32*)bufQ;                        // aliased: bf16 x (consumed before bufQ written)
  float* As = (float*)take((size_t)N * NHEAD * 4);
  float* Ad = (float*)take((size_t)N * NHEAD * 4);
  int* row_start = (int*)take((size_t)(N + 1) * 4);
  int* csr = (int*)take((size_t)E * 4);
  int2* ebuf = (int2*)take((size_t)E * 8);
  int* bcnt = (int*)take(256 * 4);
  int* bbase = (int*)take(256 * 4);
  int* bcur = (int*)take(256 * 4);
  int* cnt = (int*)take((size_t)N * 4);       // fallback
  int* cursor = (int*)take((size_t)N * 4);    // fallback
  int* blocksum = (int*)take((size_t)NB * 4); // fallback
  int* blockpre = (int*)take((size_t)NB * 4); // fallback
  unsigned short* wt16 = (unsigned short*)take((size_t)3 * WT_STRIDE * 2);

  if (off > ws_size) {
    zero_kernel<<<(out_size + 255) / 256, 256, 0, stream>>>((int*)d_out, out_size);
    return;
  }

  const int* esrc = edge_index;
  const int* edst = edge_index + E;

  long long n64 = (long long)N * 64;
  long long prep_items = n64 + 3 * 16384 + 3 * 2048 + 256 + (long long)G * 10;
  prep_kernel<<<(int)((prep_items + 255) / 256), 256, 0, stream>>>(
      x, Wl[0], Wl[1], Wl[2], asr[0], asr[1], asr[2], adr[0], adr[1], adr[2], bh,
      Xa, wt16, bcnt, (float*)d_out, n64, 256, G);

  int echunks = (E + CHUNK - 1) / CHUNK;
  if (staged) {
    bincnt_lds<<<echunks, 256, 0, stream>>>(edst, bcnt, E, N);
    bscan_kernel<<<1, 256, 0, stream>>>(bcnt, bbase, bcur, NBKT);
    binscatter_staged<<<echunks, 256, 0, stream>>>(esrc, edst, bcur, ebuf, E, N);
    bucket_finalize<<<NBKT, 256, 0, stream>>>(ebuf, bbase, row_start, csr, NBKT, E, N);
  } else {
    zero_kernel<<<(N + 255) / 256, 256, 0, stream>>>(cnt, N);
    hist_kernel<<<(E + 255) / 256, 256, 0, stream>>>(edst, cnt, E, N);
    scan_pass1<<<NB, 256, 0, stream>>>(cnt, blocksum, N);
    scan_pass2<<<1, 256, 0, stream>>>(blocksum, blockpre, row_start, NB, N);
    scan_pass3<<<NB, 256, 0, stream>>>(cnt, blockpre, row_start, cursor, N);
    scatter_kernel<<<(E + 255) / 256, 256, 0, stream>>>(esrc, edst, cursor, csr, E, N);
  }

  int gemm_grid = (N + 31) / 32;
  int agg_grid = (N + 3) / 4;

  // layer 0
  gemm_mfma<<<gemm_grid, 256, 0, stream>>>(Xa, wt16, H16, As, Ad, N);
  agg_kernel<false><<<agg_grid, 256, 0, stream>>>(H16, As, Ad, row_start, csr, bias[0], X16, N);
  // layer 1
  gemm_mfma<<<gemm_grid, 256, 0, stream>>>(X16, wt16 + WT_STRIDE, H16, As, Ad, N);
  agg_kernel<false><<<agg_grid, 256, 0, stream>>>(H16, As, Ad, row_start, csr, bias[1], X16, N);
  // layer 2 (agg -> fp32 bufQ; Xa no longer needed)
  gemm_mfma<<<gemm_grid, 256, 0, stream>>>(X16, wt16 + 2 * WT_STRIDE, H16, As, Ad, N);
  agg_kernel<true><<<agg_grid, 256, 0, stream>>>(H16, As, Ad, row_start, csr, bias[2], bufQ, N);

  pool_logits<<<(N + 63) / 64, 128, 0, stream>>>(bufQ, batch, Wh, (float*)d_out, N, G);
}